// Round 6
// baseline (1100.479 us; speedup 1.0000x reference)
//
#include <hip/hip_runtime.h>
#include <cstdint>
#include <cstddef>

using u64 = unsigned long long;
using i64 = long long;

#define DEVI __device__ __forceinline__

// ---------------------------------------------------------------- reductions
DEVI double waveRed(double v) {
    #pragma unroll
    for (int o = 32; o > 0; o >>= 1) v += __shfl_down(v, o, 64);
    return v;
}

// ---------------------------------------------------------------- conv0 stats (np-f32: FMA chain, (kh,kw,ci) order)
__global__ __launch_bounds__(256, 1) void conv0_sums3(const float* __restrict__ x,
                                                      const float* __restrict__ w0,
                                                      double* __restrict__ sum,
                                                      double* __restrict__ sumsq) {
    __shared__ float xs[3072];
    __shared__ float wsh[864];          // 32 co * 27, tap-major
    __shared__ double redS[4][32], redS2[4][32];
    int tid = threadIdx.x, n = blockIdx.y, co0 = blockIdx.x * 32;
    for (int i = tid; i < 3072; i += 256) xs[i] = x[n * 3072 + i];
    for (int i = tid; i < 864; i += 256) {
        int co = i / 27, j = i % 27;    // j = tap-major (kh*3+kw)*3 + ci
        int ci = j % 3, k = j / 3;
        wsh[i] = w0[(co0 + co) * 27 + ci * 9 + k];
    }
    __syncthreads();

    float xv[4][27];
    #pragma unroll
    for (int k = 0; k < 4; ++k) {
        int pos = tid + k * 256, h = pos >> 5, w = pos & 31;
        #pragma unroll
        for (int kh = 0; kh < 3; ++kh) {
            #pragma unroll
            for (int kw = 0; kw < 3; ++kw) {
                #pragma unroll
                for (int ci = 0; ci < 3; ++ci) {
                    int ih = h + kh - 1, iw = w + kw - 1;
                    bool ok = (unsigned)ih < 32u && (unsigned)iw < 32u;
                    xv[k][(kh * 3 + kw) * 3 + ci] = ok ? xs[ci * 1024 + ih * 32 + iw] : 0.0f;
                }
            }
        }
    }
    int lane = tid & 63, wv = tid >> 6;
    for (int co = 0; co < 32; ++co) {
        #pragma clang fp contract(off)
        const float* wp = &wsh[co * 27];
        float a0 = 0.f, a1 = 0.f, a2 = 0.f, a3 = 0.f;
        #pragma unroll
        for (int j = 0; j < 27; ++j) {
            float wj = wp[j];
            a0 = __builtin_fmaf(xv[0][j], wj, a0);
            a1 = __builtin_fmaf(xv[1][j], wj, a1);
            a2 = __builtin_fmaf(xv[2][j], wj, a2);
            a3 = __builtin_fmaf(xv[3][j], wj, a3);
        }
        double y0 = a0, y1 = a1, y2 = a2, y3 = a3;
        double s  = (y0 + y1) + (y2 + y3);
        double s2 = (y0 * y0 + y1 * y1) + (y2 * y2 + y3 * y3);
        s = waveRed(s); s2 = waveRed(s2);
        if (lane == 0) { redS[wv][co] = s; redS2[wv][co] = s2; }
    }
    __syncthreads();
    if (tid < 32) {
        atomicAdd(&sum[co0 + tid], (redS[0][tid] + redS[1][tid]) + (redS[2][tid] + redS[3][tid]));
    } else if (tid < 64) {
        int c = tid - 32;
        atomicAdd(&sumsq[co0 + c], (redS2[0][c] + redS2[1][c]) + (redS2[2][c] + redS2[3][c]));
    }
}

__global__ void finalize_c0(const double* __restrict__ sum, const double* __restrict__ sumsq,
                            const float* __restrict__ g, const float* __restrict__ b,
                            double* __restrict__ M, double* __restrict__ A,
                            double* __restrict__ BB) {
    int c = threadIdx.x;    // 128
    double m = sum[c] / 262144.0;
    double var = sumsq[c] / 262144.0 - m * m;
    M[c]  = m;
    A[c]  = (double)g[c] / sqrt(var + 1e-5);
    BB[c] = (double)b[c];
}

// ---------------------------------------------------------------- conv0 pack
__global__ __launch_bounds__(256, 1) void conv0_pack3(const float* __restrict__ x,
                                                      const float* __restrict__ w0,
                                                      const double* __restrict__ M,
                                                      const double* __restrict__ A,
                                                      const double* __restrict__ BB,
                                                      u64* __restrict__ A0) {
    __shared__ float xs[3072];
    __shared__ float wsh[3456];
    __shared__ double msh[128], ash[128], bsh[128];
    int tid = threadIdx.x, n = blockIdx.x >> 2;
    int pos = ((blockIdx.x & 3) << 8) + tid;
    for (int i = tid; i < 3072; i += 256) xs[i] = x[n * 3072 + i];
    for (int i = tid; i < 3456; i += 256) {
        int co = i / 27, j = i % 27;    // tap-major
        int ci = j % 3, k = j / 3;
        wsh[i] = w0[co * 27 + ci * 9 + k];
    }
    if (tid < 128) { msh[tid] = M[tid]; ash[tid] = A[tid]; bsh[tid] = BB[tid]; }
    __syncthreads();

    int h = pos >> 5, w = pos & 31;
    float xv[27];
    #pragma unroll
    for (int kh = 0; kh < 3; ++kh) {
        #pragma unroll
        for (int kw = 0; kw < 3; ++kw) {
            #pragma unroll
            for (int ci = 0; ci < 3; ++ci) {
                int ih = h + kh - 1, iw = w + kw - 1;
                bool ok = (unsigned)ih < 32u && (unsigned)iw < 32u;
                xv[(kh * 3 + kw) * 3 + ci] = ok ? xs[ci * 1024 + ih * 32 + iw] : 0.0f;
            }
        }
    }
    u64 b0 = 0, b1 = 0;
    #pragma unroll 4
    for (int co = 0; co < 128; ++co) {
        #pragma clang fp contract(off)
        float acc = 0.f;
        const float* wp = &wsh[co * 27];
        #pragma unroll
        for (int j = 0; j < 27; ++j) acc = __builtin_fmaf(xv[j], wp[j], acc);
        double t = ash[co] * ((double)acc - msh[co]) + bsh[co];
        u64 bit = t > 0.0 ? 1ull : 0ull;
        if (co < 64) b0 |= bit << co; else b1 |= bit << (co - 64);
    }
    size_t p = (size_t)n * 1024 + pos;
    A0[p * 2] = b0; A0[p * 2 + 1] = b1;
}

// ---------------------------------------------------------------- weight bit-pack
__global__ __launch_bounds__(256) void pack_w(const float* __restrict__ w,
                                              u64* __restrict__ Wb, int Ci, int Co) {
    int widx = blockIdx.x * 4 + (threadIdx.x >> 6);
    int lane = threadIdx.x & 63;
    int CW = Ci >> 6;
    int co = widx % Co;
    int rest = widx / Co;
    int cw = rest % CW;
    int k = rest / CW;
    int kh = k / 3, kw = k % 3;
    int ci = (cw << 6) | lane;
    float v = w[((size_t)(co * Ci + ci) * 3 + kh) * 3 + kw];
    u64 m = __ballot(v > 0.0f);
    if (lane == 0) Wb[widx] = m;
}

// ---------------------------------------------------------------- pooled bconv, row-inner j-complete (R6 new)
// Block = one (n, ho) output row x co-group (CPB co's, WSPLIT wo-groups).
// 4 input rows staged zero-padded in LDS. Per output wo (j): loop the 4 rows;
// load that row's 4 window columns (4x ds_read_b128 broadcast, constant offs)
// and immediately accumulate the 4 pool candidates: row r feeds (py=0,kh=r)
// and (py=1,kh=r-1) - both compile-time branches. Live state: 18 u64 chunk
// weights + 8 u64 transient x + q[WOT*4] ints. No sliding window, no remat
// pressure. Pad handling: zero taps counted then corrected via P[9] weight
// popcounts (proven bconv_lds math) -> bit-identical.
template <int CW, int CO, int HI, int CPB>
__global__ __launch_bounds__(256, 2) void bconv_pool4(const u64* __restrict__ A,
                                                      const u64* __restrict__ Wb,
                                                      short* __restrict__ dots,
                                                      i64* __restrict__ sums) {
    constexpr int WI = HI, HO = HI / 2, WO = HI / 2;
    constexpr int BPR = CO / CPB;
    constexpr int WSPLIT = 256 / CPB;
    constexpr int WOT = WO / WSPLIT;
    constexpr int CH = CW / 2;
    constexpr int LROW = (WI + 2) * CW;
    constexpr int NWORD = 4 * LROW;

    __shared__ alignas(16) u64 xs[NWORD];

    const int tid = threadIdx.x;
    const int bid = blockIdx.x;
    const int coh = bid % BPR;
    const int rest = bid / BPR;
    const int ho = rest % HO;
    const int n = rest / HO;
    const int co = coh * CPB + (tid % CPB);
    const int wo0 = (tid / CPB) * WOT;
    const int hbase = 2 * ho - 1;

    // ---- stage 4 rows (zero row/col padding) ----
    const u64* An = A + (size_t)n * HI * WI * CW;
    for (int i = tid; i < NWORD; i += 256) {
        int r = i / LROW;
        int rem = i - r * LROW;
        int c = rem / CW;
        int ch = rem - c * CW;
        int ih = hbase + r, iw = c - 1;
        u64 v = 0;
        if ((unsigned)ih < (unsigned)HI && (unsigned)iw < (unsigned)WI)
            v = An[(size_t)(ih * WI + iw) * CW + ch];
        xs[i] = v;
    }
    __syncthreads();

    int q[WOT * 4];
    #pragma unroll
    for (int i = 0; i < WOT * 4; ++i) q[i] = 0;
    int P[9];
    #pragma unroll
    for (int k = 0; k < 9; ++k) P[k] = 0;

    #pragma unroll 1
    for (int ch2 = 0; ch2 < CH; ++ch2) {
        u64 wa[9], wb[9];
        #pragma unroll
        for (int k = 0; k < 9; ++k) {
            wa[k] = Wb[(size_t)(k * CW + 2 * ch2) * CO + co];
            wb[k] = Wb[(size_t)(k * CW + 2 * ch2 + 1) * CO + co];
        }
        #pragma unroll
        for (int k = 0; k < 9; ++k) P[k] += __popcll(wa[k]) + __popcll(wb[k]);

        #pragma unroll
        for (int j = 0; j < WOT; ++j) {
            const int cb = 2 * (wo0 + j);     // LDS col of window col 0
            #pragma unroll
            for (int r = 0; r < 4; ++r) {
                const u64* rp = &xs[r * LROW + cb * CW + 2 * ch2];
                const ulonglong2 v0 = *(const ulonglong2*)(rp);
                const ulonglong2 v1 = *(const ulonglong2*)(rp + CW);
                const ulonglong2 v2 = *(const ulonglong2*)(rp + 2 * CW);
                const ulonglong2 v3 = *(const ulonglong2*)(rp + 3 * CW);
                if (r <= 2) {                 // py = 0, kh = r
                    q[j * 4 + 0] += __popcll(v0.x ^ wa[r * 3 + 0]) + __popcll(v0.y ^ wb[r * 3 + 0])
                                  + __popcll(v1.x ^ wa[r * 3 + 1]) + __popcll(v1.y ^ wb[r * 3 + 1])
                                  + __popcll(v2.x ^ wa[r * 3 + 2]) + __popcll(v2.y ^ wb[r * 3 + 2]);
                    q[j * 4 + 1] += __popcll(v1.x ^ wa[r * 3 + 0]) + __popcll(v1.y ^ wb[r * 3 + 0])
                                  + __popcll(v2.x ^ wa[r * 3 + 1]) + __popcll(v2.y ^ wb[r * 3 + 1])
                                  + __popcll(v3.x ^ wa[r * 3 + 2]) + __popcll(v3.y ^ wb[r * 3 + 2]);
                }
                if (r >= 1) {                 // py = 1, kh = r-1
                    const int kh = r - 1;
                    q[j * 4 + 2] += __popcll(v0.x ^ wa[kh * 3 + 0]) + __popcll(v0.y ^ wb[kh * 3 + 0])
                                  + __popcll(v1.x ^ wa[kh * 3 + 1]) + __popcll(v1.y ^ wb[kh * 3 + 1])
                                  + __popcll(v2.x ^ wa[kh * 3 + 2]) + __popcll(v2.y ^ wb[kh * 3 + 2]);
                    q[j * 4 + 3] += __popcll(v1.x ^ wa[kh * 3 + 0]) + __popcll(v1.y ^ wb[kh * 3 + 0])
                                  + __popcll(v2.x ^ wa[kh * 3 + 1]) + __popcll(v2.y ^ wb[kh * 3 + 1])
                                  + __popcll(v3.x ^ wa[kh * 3 + 2]) + __popcll(v3.y ^ wb[kh * 3 + 2]);
                }
            }
        }
    }

    // ---- epilogue: pad correction, pooling max, store (bconv_lds math) ----
    const int prT = P[0] + P[1] + P[2];
    const int prB = P[6] + P[7] + P[8];
    const int pcL = P[0] + P[3] + P[6];
    const int pcR = P[2] + P[5] + P[8];
    const int k00 = P[0], k02 = P[2], k20 = P[6], k22 = P[8];

    int accS = 0, accS2 = 0;
    #pragma unroll
    for (int j = 0; j < WOT; ++j) {
        const int wo = wo0 + j;
        int best = -(1 << 30);
        #pragma unroll
        for (int py = 0; py < 2; ++py) {
            #pragma unroll
            for (int px = 0; px < 2; ++px) {
                const int hc = 2 * ho + py, wc = 2 * wo + px;
                const int rT = (hc == 0), rB = (hc == HI - 1);
                const int cL = (wc == 0), cR = (wc == WI - 1);
                const int nv = (3 - rT - rB) * (3 - cL - cR);
                const int pad = (rT ? prT : 0) + (rB ? prB : 0) + (cL ? pcL : 0) + (cR ? pcR : 0)
                              - ((rT & cL) ? k00 : 0) - ((rT & cR) ? k02 : 0)
                              - ((rB & cL) ? k20 : 0) - ((rB & cR) ? k22 : 0);
                const int d = 64 * CW * nv + 2 * pad - 2 * q[j * 4 + py * 2 + px];
                best = d > best ? d : best;
            }
        }
        dots[(size_t)((n * HO + ho) * WO + wo) * CO + co] = (short)best;
        accS += best;
        accS2 += best * best;
    }
    atomicAdd((u64*)&sums[co], (u64)(i64)accS);
    atomicAdd((u64*)&sums[CO + co], (u64)(i64)accS2);
}

// ---------------------------------------------------------------- no-LDS sliding-window bconv (L2: CW=2, non-pool; R5 proven)
template <int CO, int HI>
__global__ __launch_bounds__(256, 2) void bconv_gslide2(const u64* __restrict__ A,
                                                        const u64* __restrict__ Wb,
                                                        short* __restrict__ dots,
                                                        i64* __restrict__ sums) {
    constexpr int WI = HI;
    constexpr int CW = 2;
    static_assert(CO == 256, "block covers all co");
    const int tid = threadIdx.x;
    const int bid = blockIdx.x;        // = n*HI + ho
    const int ho = bid % HI;
    const int n = bid / HI;
    const int co = tid;

    u64 wa[9], wb[9];
    #pragma unroll
    for (int k = 0; k < 9; ++k) {
        wa[k] = Wb[(size_t)(k * CW) * CO + co];
        wb[k] = Wb[(size_t)(k * CW + 1) * CO + co];
    }

    const u64* An = A + (size_t)n * HI * WI * CW;
    int rmask[3];
    const u64* rowp[3];
    #pragma unroll
    for (int r = 0; r < 3; ++r) {
        int ih = ho - 1 + r;
        rmask[r] = ((unsigned)ih < (unsigned)HI) ? -1 : 0;
        int ihc = ih < 0 ? 0 : (ih > HI - 1 ? HI - 1 : ih);
        rowp[r] = An + (size_t)ihc * WI * CW;
    }
    const int vr = 3 - (ho == 0) - (ho == HI - 1);

    u64 wx[3][3], wy[3][3];
    #pragma unroll
    for (int c = 0; c < 2; ++c) {
        const int iwc = (c - 1) < 0 ? 0 : (c - 1);
        #pragma unroll
        for (int r = 0; r < 3; ++r) {
            const ulonglong2 v = *(const ulonglong2*)(rowp[r] + (size_t)iwc * CW);
            wx[r][c] = v.x; wy[r][c] = v.y;
        }
    }

    int s = 0, s2 = 0;
    #pragma unroll
    for (int j = 0; j < WI; ++j) {
        {
            const int iwc = (j + 1) > WI - 1 ? WI - 1 : (j + 1);
            const int sl = (j + 2) % 3;
            #pragma unroll
            for (int r = 0; r < 3; ++r) {
                const ulonglong2 v = *(const ulonglong2*)(rowp[r] + (size_t)iwc * CW);
                wx[r][sl] = v.x; wy[r][sl] = v.y;
            }
        }
        const int vc = 3 - (j == 0) - (j == WI - 1);
        int q = 0;
        #pragma unroll
        for (int kh = 0; kh < 3; ++kh) {
            #pragma unroll
            for (int kw = 0; kw < 3; ++kw) {
                const int c = j + kw;          // absolute window column
                const int sl = c % 3;
                if (c == 0 || c == WI + 1) continue;   // compile-time pad taps
                const int add = __popcll(wx[kh][sl] ^ wa[kh * 3 + kw])
                              + __popcll(wy[kh][sl] ^ wb[kh * 3 + kw]);
                q += add & rmask[kh];
            }
        }
        const int dot = vr * vc * CW * 64 - 2 * q;
        dots[(size_t)((n * HI + ho) * WI + j) * CO + co] = (short)dot;
        s += dot;
        s2 += dot * dot;
    }
    atomicAdd((u64*)&sums[co], (u64)(i64)s);
    atomicAdd((u64*)&sums[CO + co], (u64)(i64)s2);
}

// ---------------------------------------------------------------- LDS-staged binary conv (R1 proven kernel; L4, L5)
template <int CW, int CO, int HI, bool POOL>
__global__ __launch_bounds__(256, 2) void bconv_lds(const u64* __restrict__ A,
                                                    const u64* __restrict__ Wb,
                                                    short* __restrict__ dots,
                                                    i64* __restrict__ sums) {
    constexpr int WI = HI;
    constexpr int HO = POOL ? HI / 2 : HI;
    constexpr int WO = POOL ? WI / 2 : WI;
    constexpr int NR = POOL ? 4 : 3;
    constexpr int NCOL = POOL ? 4 : 3;
    constexpr int CPB = (CO < 256) ? CO : 256;
    constexpr int BPR = CO / CPB;
    constexpr int WSPLIT = 256 / CPB;
    constexpr int WOT = WO / WSPLIT;
    constexpr int CH = CW / 2;
    constexpr int LROW = (WI + 2) * CW;
    constexpr int NWORD = NR * LROW;
    constexpr int NC = POOL ? 4 : 1;

    __shared__ alignas(16) u64 xs[NWORD];

    const int tid = threadIdx.x;
    const int bid = blockIdx.x;
    const int coh = bid % BPR;
    const int rest = bid / BPR;
    const int ho = rest % HO;
    const int n = rest / HO;
    const int co = coh * CPB + (tid % CPB);
    const int wo0 = (tid / CPB) * WOT;
    const int hbase = POOL ? 2 * ho - 1 : ho - 1;

    const u64* An = A + (size_t)n * HI * WI * CW;
    for (int i = tid; i < NWORD; i += 256) {
        int r = i / LROW;
        int rem = i - r * LROW;
        int c = rem / CW;
        int ch = rem - c * CW;
        int ih = hbase + r, iw = c - 1;
        u64 v = 0;
        if ((unsigned)ih < (unsigned)HI && (unsigned)iw < (unsigned)WI)
            v = An[(size_t)(ih * WI + iw) * CW + ch];
        xs[i] = v;
    }
    __syncthreads();

    int q[WOT * NC];
    #pragma unroll
    for (int i = 0; i < WOT * NC; ++i) q[i] = 0;
    int P[9];
    #pragma unroll
    for (int k = 0; k < 9; ++k) P[k] = 0;

    const int c0 = POOL ? 2 * wo0 : wo0;

    #pragma unroll 1
    for (int ch2 = 0; ch2 < CH; ++ch2) {
        u64 wa[9], wb[9];
        #pragma unroll
        for (int k = 0; k < 9; ++k) {
            wa[k] = Wb[(size_t)(k * CW + 2 * ch2) * CO + co];
            wb[k] = Wb[(size_t)(k * CW + 2 * ch2 + 1) * CO + co];
        }
        #pragma unroll
        for (int k = 0; k < 9; ++k) P[k] += __popcll(wa[k]) + __popcll(wb[k]);

        u64 wx[NR][NCOL], wy[NR][NCOL];
        #pragma unroll
        for (int s = 0; s < 2; ++s) {
            #pragma unroll
            for (int r = 0; r < NR; ++r) {
                const ulonglong2 v = *(const ulonglong2*)&xs[r * LROW + (c0 + s) * CW + 2 * ch2];
                wx[r][s] = v.x; wy[r][s] = v.y;
            }
        }
        #pragma unroll
        for (int j = 0; j < WOT; ++j) {
            if constexpr (!POOL) {
                #pragma unroll
                for (int r = 0; r < NR; ++r) {
                    const ulonglong2 v = *(const ulonglong2*)&xs[r * LROW + (c0 + j + 2) * CW + 2 * ch2];
                    wx[r][(j + 2) % 3] = v.x; wy[r][(j + 2) % 3] = v.y;
                }
                int qq = 0;
                #pragma unroll
                for (int kh = 0; kh < 3; ++kh) {
                    #pragma unroll
                    for (int kw = 0; kw < 3; ++kw) {
                        const int sl = (j + kw) % 3;
                        qq += __popcll(wx[kh][sl] ^ wa[kh * 3 + kw])
                            + __popcll(wy[kh][sl] ^ wb[kh * 3 + kw]);
                    }
                }
                q[j] += qq;
            } else {
                #pragma unroll
                for (int s = 2; s < 4; ++s) {
                    const int sl = (2 * j + s) & 3;
                    #pragma unroll
                    for (int r = 0; r < NR; ++r) {
                        const ulonglong2 v = *(const ulonglong2*)&xs[r * LROW + (c0 + 2 * j + s) * CW + 2 * ch2];
                        wx[r][sl] = v.x; wy[r][sl] = v.y;
                    }
                }
                #pragma unroll
                for (int py = 0; py < 2; ++py) {
                    #pragma unroll
                    for (int px = 0; px < 2; ++px) {
                        int qq = 0;
                        #pragma unroll
                        for (int kh = 0; kh < 3; ++kh) {
                            #pragma unroll
                            for (int kw = 0; kw < 3; ++kw) {
                                const int sl = (2 * j + px + kw) & 3;
                                qq += __popcll(wx[py + kh][sl] ^ wa[kh * 3 + kw])
                                    + __popcll(wy[py + kh][sl] ^ wb[kh * 3 + kw]);
                            }
                        }
                        q[j * 4 + py * 2 + px] += qq;
                    }
                }
            }
        }
    }

    const int prT = P[0] + P[1] + P[2];
    const int prB = P[6] + P[7] + P[8];
    const int pcL = P[0] + P[3] + P[6];
    const int pcR = P[2] + P[5] + P[8];
    const int k00 = P[0], k02 = P[2], k20 = P[6], k22 = P[8];

    int accS = 0, accS2 = 0;
    #pragma unroll
    for (int j = 0; j < WOT; ++j) {
        const int wo = wo0 + j;
        int best;
        if constexpr (!POOL) {
            const int rT = (ho == 0), rB = (ho == HI - 1);
            const int cL = (wo == 0), cR = (wo == WI - 1);
            const int nv = (3 - rT - rB) * (3 - cL - cR);
            const int pad = (rT ? prT : 0) + (rB ? prB : 0) + (cL ? pcL : 0) + (cR ? pcR : 0)
                          - ((rT & cL) ? k00 : 0) - ((rT & cR) ? k02 : 0)
                          - ((rB & cL) ? k20 : 0) - ((rB & cR) ? k22 : 0);
            best = 64 * CW * nv + 2 * pad - 2 * q[j];
        } else {
            best = -(1 << 30);
            #pragma unroll
            for (int py = 0; py < 2; ++py) {
                #pragma unroll
                for (int px = 0; px < 2; ++px) {
                    const int hc = 2 * ho + py, wc = 2 * wo + px;
                    const int rT = (hc == 0), rB = (hc == HI - 1);
                    const int cL = (wc == 0), cR = (wc == WI - 1);
                    const int nv = (3 - rT - rB) * (3 - cL - cR);
                    const int pad = (rT ? prT : 0) + (rB ? prB : 0) + (cL ? pcL : 0) + (cR ? pcR : 0)
                                  - ((rT & cL) ? k00 : 0) - ((rT & cR) ? k02 : 0)
                                  - ((rB & cL) ? k20 : 0) - ((rB & cR) ? k22 : 0);
                    const int d = 64 * CW * nv + 2 * pad - 2 * q[j * 4 + py * 2 + px];
                    best = d > best ? d : best;
                }
            }
        }
        dots[(size_t)((n * HO + ho) * WO + wo) * CO + co] = (short)best;
        accS += best;
        accS2 += best * best;
    }
    atomicAdd((u64*)&sums[co], (u64)(i64)accS);
    atomicAdd((u64*)&sums[CO + co], (u64)(i64)accS2);
}

__global__ void finalize_bn(const i64* __restrict__ sums,
                            const float* __restrict__ g, const float* __restrict__ b,
                            int CO, double cnt, double* __restrict__ M,
                            double* __restrict__ A, double* __restrict__ BB) {
    int c = blockIdx.x * blockDim.x + threadIdx.x;
    if (c >= CO) return;
    double m = (double)sums[c] / cnt;
    double var = (double)sums[CO + c] / cnt - m * m;
    M[c]  = m;
    A[c]  = (double)g[c] / sqrt(var + 1e-5);
    BB[c] = (double)b[c];
}

// ---------------------------------------------------------------- binarize + bit-pack
template <int CO>
__global__ __launch_bounds__(256) void binpack_k(const short* __restrict__ xin,
                                                 const double* __restrict__ M,
                                                 const double* __restrict__ A,
                                                 const double* __restrict__ BB,
                                                 u64* __restrict__ Ab) {
    constexpr int CWo = CO / 64;
    int widx = blockIdx.x * 4 + (threadIdx.x >> 6);
    int lane = threadIdx.x & 63;
    int w = widx & (CWo - 1);
    int p = widx / CWo;
    int c = (w << 6) | lane;
    double t = A[c] * ((double)xin[(size_t)p * CO + c] - M[c]) + BB[c];
    u64 m = __ballot(t > 0.0);
    if (lane == 0) Ab[widx] = m;
}

// ---------------------------------------------------------------- FC head
__global__ __launch_bounds__(256) void fc_k(const short* __restrict__ x5,
                                            const double* __restrict__ M,
                                            const double* __restrict__ A,
                                            const double* __restrict__ BB,
                                            const float* __restrict__ wfc,
                                            const float* __restrict__ bfc,
                                            float* __restrict__ out) {
    int n = blockIdx.x / 10, k = blockIdx.x % 10;
    double acc = 0.0;
    for (int i = threadIdx.x; i < 8192; i += 256) {
        int c = i >> 4, hw = i & 15, h = hw >> 2, ww = hw & 3;
        double t = A[c] * ((double)x5[(size_t)((n * 4 + h) * 4 + ww) * 512 + c] - M[c]) + BB[c];
        t = t < -1.0 ? -1.0 : (t > 1.0 ? 1.0 : t);
        acc += t * (double)wfc[(size_t)k * 8192 + i];
    }
    acc = waveRed(acc);
    __shared__ double sd[4];
    if ((threadIdx.x & 63) == 0) sd[threadIdx.x >> 6] = acc;
    __syncthreads();
    if (threadIdx.x == 0)
        out[n * 10 + k] = (float)(sd[0] + sd[1] + sd[2] + sd[3] + (double)bfc[k]);
}

// ---------------------------------------------------------------- launch
extern "C" void kernel_launch(void* const* d_in, const int* in_sizes, int n_in,
                              void* d_out, int out_size, void* d_ws, size_t ws_size,
                              hipStream_t stream) {
    (void)in_sizes; (void)n_in; (void)out_size; (void)ws_size;

    const float* x   = (const float*)d_in[0];
    const float* w0  = (const float*)d_in[1];
    const float* g0  = (const float*)d_in[2];
    const float* b0  = (const float*)d_in[3];
    const float* w1  = (const float*)d_in[4];
    const float* g1  = (const float*)d_in[5];
    const float* b1  = (const float*)d_in[6];
    const float* w2  = (const float*)d_in[7];
    const float* g2  = (const float*)d_in[8];
    const float* b2  = (const float*)d_in[9];
    const float* w3  = (const float*)d_in[10];
    const float* g3  = (const float*)d_in[11];
    const float* b3  = (const float*)d_in[12];
    const float* w4  = (const float*)d_in[13];
    const float* g4  = (const float*)d_in[14];
    const float* b4  = (const float*)d_in[15];
    const float* w5  = (const float*)d_in[16];
    const float* g5  = (const float*)d_in[17];
    const float* b5  = (const float*)d_in[18];
    const float* wfc = (const float*)d_in[19];
    const float* bfc = (const float*)d_in[20];
    float* out = (float*)d_out;

    // ---- workspace layout (~43.2 MB) ----
    char* ws = (char*)d_ws;
    double* sum0   = (double*)ws;                  // 128
    double* sumsq0 = sum0 + 128;                   // 128
    i64* isums = (i64*)(sumsq0 + 128);             // 5 layers * 1024
    // zero span: 2048 + 40960 = 43008 bytes
    double* M  = (double*)(ws + 65536);            // 6*512
    double* A  = M + 3072;
    double* BB = A + 3072;
    char* p = ws + 65536 + 73728;
    u64* A0 = (u64*)p;  p += (size_t)262144 * 2 * 8;   // 4 MiB
    u64* A1 = (u64*)p;  p += (size_t)65536 * 2 * 8;    // 1 MiB
    u64* A2 = (u64*)p;  p += (size_t)65536 * 4 * 8;    // 2 MiB
    u64* A3 = (u64*)p;  p += (size_t)16384 * 4 * 8;    // 0.5 MiB
    u64* A4 = (u64*)p;  p += (size_t)16384 * 8 * 8;    // 1 MiB
    u64* Wb1 = (u64*)p; p += 2304 * 8;
    u64* Wb2 = (u64*)p; p += 4608 * 8;
    u64* Wb3 = (u64*)p; p += 9216 * 8;
    u64* Wb4 = (u64*)p; p += 18432 * 8;
    u64* Wb5 = (u64*)p; p += 36864 * 8;
    p = (char*)(((uintptr_t)p + 255) & ~(uintptr_t)255);
    short* dots = (short*)p;                       // max 65536*256*2 = 33.5 MB

    hipMemsetAsync(d_ws, 0, 43008, stream);

    // weight bit-packs
    pack_w<<<576,  256, 0, stream>>>(w1, Wb1, 128, 128);
    pack_w<<<1152, 256, 0, stream>>>(w2, Wb2, 128, 256);
    pack_w<<<2304, 256, 0, stream>>>(w3, Wb3, 256, 256);
    pack_w<<<4608, 256, 0, stream>>>(w4, Wb4, 256, 512);
    pack_w<<<9216, 256, 0, stream>>>(w5, Wb5, 512, 512);

    // conv0 (np-f32 FMA (kh,kw,ci)) + BN0 + pack
    conv0_sums3<<<dim3(4, 256), 256, 0, stream>>>(x, w0, sum0, sumsq0);
    finalize_c0<<<1, 128, 0, stream>>>(sum0, sumsq0, g0, b0, M, A, BB);
    conv0_pack3<<<1024, 256, 0, stream>>>(x, w0, M, A, BB, A0);

    // L1: 128->128 @32x32, pool -> 16x16  (NEW row-inner pooled kernel, CPB=64 -> WOT=4)
    bconv_pool4<2, 128, 32, 64><<<8192, 256, 0, stream>>>(A0, Wb1, dots, isums);
    finalize_bn<<<1, 128, 0, stream>>>(isums, g1, b1, 128, 65536.0, M + 512, A + 512, BB + 512);
    binpack_k<128><<<32768, 256, 0, stream>>>(dots, M + 512, A + 512, BB + 512, A1);

    // L2: 128->256 @16x16 (no-LDS sliding-window kernel, R5 proven)
    bconv_gslide2<256, 16><<<4096, 256, 0, stream>>>(A1, Wb2, dots, isums + 1024);
    finalize_bn<<<1, 256, 0, stream>>>(isums + 1024, g2, b2, 256, 65536.0, M + 1024, A + 1024, BB + 1024);
    binpack_k<256><<<65536, 256, 0, stream>>>(dots, M + 1024, A + 1024, BB + 1024, A2);

    // L3: 256->256 @16x16, pool -> 8x8  (NEW row-inner pooled kernel, CPB=128 -> WOT=4)
    bconv_pool4<4, 256, 16, 128><<<4096, 256, 0, stream>>>(A2, Wb3, dots, isums + 2048);
    finalize_bn<<<1, 256, 0, stream>>>(isums + 2048, g3, b3, 256, 16384.0, M + 1536, A + 1536, BB + 1536);
    binpack_k<256><<<16384, 256, 0, stream>>>(dots, M + 1536, A + 1536, BB + 1536, A3);

    // L4: 256->512 @8x8 (R1 bconv_lds exact)
    bconv_lds<4, 512, 8, false><<<4096, 256, 0, stream>>>(A3, Wb4, dots, isums + 3072);
    finalize_bn<<<1, 512, 0, stream>>>(isums + 3072, g4, b4, 512, 16384.0, M + 2048, A + 2048, BB + 2048);
    binpack_k<512><<<32768, 256, 0, stream>>>(dots, M + 2048, A + 2048, BB + 2048, A4);

    // L5: 512->512 @8x8, pool -> 4x4 (R1 bconv_lds exact)
    bconv_lds<8, 512, 8, true><<<2048, 256, 0, stream>>>(A4, Wb5, dots, isums + 4096);
    finalize_bn<<<1, 512, 0, stream>>>(isums + 4096, g5, b5, 512, 4096.0, M + 2560, A + 2560, BB + 2560);

    // FC head
    fc_k<<<2560, 256, 0, stream>>>(dots, M + 2560, A + 2560, BB + 2560, wfc, bfc, out);
}

// Round 7
// 770.370 us; speedup vs baseline: 1.4285x; 1.4285x over previous
//
#include <hip/hip_runtime.h>
#include <cstdint>
#include <cstddef>

using u64 = unsigned long long;
using i64 = long long;

#define DEVI __device__ __forceinline__

// ---------------------------------------------------------------- reductions
DEVI double waveRed(double v) {
    #pragma unroll
    for (int o = 32; o > 0; o >>= 1) v += __shfl_down(v, o, 64);
    return v;
}

// ---------------------------------------------------------------- conv0 stats (np-f32: FMA chain, (kh,kw,ci) order)
__global__ __launch_bounds__(256, 1) void conv0_sums3(const float* __restrict__ x,
                                                      const float* __restrict__ w0,
                                                      double* __restrict__ sum,
                                                      double* __restrict__ sumsq) {
    __shared__ float xs[3072];
    __shared__ float wsh[864];          // 32 co * 27, tap-major
    __shared__ double redS[4][32], redS2[4][32];
    int tid = threadIdx.x, n = blockIdx.y, co0 = blockIdx.x * 32;
    for (int i = tid; i < 3072; i += 256) xs[i] = x[n * 3072 + i];
    for (int i = tid; i < 864; i += 256) {
        int co = i / 27, j = i % 27;    // j = tap-major (kh*3+kw)*3 + ci
        int ci = j % 3, k = j / 3;
        wsh[i] = w0[(co0 + co) * 27 + ci * 9 + k];
    }
    __syncthreads();

    float xv[4][27];
    #pragma unroll
    for (int k = 0; k < 4; ++k) {
        int pos = tid + k * 256, h = pos >> 5, w = pos & 31;
        #pragma unroll
        for (int kh = 0; kh < 3; ++kh) {
            #pragma unroll
            for (int kw = 0; kw < 3; ++kw) {
                #pragma unroll
                for (int ci = 0; ci < 3; ++ci) {
                    int ih = h + kh - 1, iw = w + kw - 1;
                    bool ok = (unsigned)ih < 32u && (unsigned)iw < 32u;
                    xv[k][(kh * 3 + kw) * 3 + ci] = ok ? xs[ci * 1024 + ih * 32 + iw] : 0.0f;
                }
            }
        }
    }
    int lane = tid & 63, wv = tid >> 6;
    for (int co = 0; co < 32; ++co) {
        #pragma clang fp contract(off)
        const float* wp = &wsh[co * 27];
        float a0 = 0.f, a1 = 0.f, a2 = 0.f, a3 = 0.f;
        #pragma unroll
        for (int j = 0; j < 27; ++j) {
            float wj = wp[j];
            a0 = __builtin_fmaf(xv[0][j], wj, a0);
            a1 = __builtin_fmaf(xv[1][j], wj, a1);
            a2 = __builtin_fmaf(xv[2][j], wj, a2);
            a3 = __builtin_fmaf(xv[3][j], wj, a3);
        }
        double y0 = a0, y1 = a1, y2 = a2, y3 = a3;
        double s  = (y0 + y1) + (y2 + y3);
        double s2 = (y0 * y0 + y1 * y1) + (y2 * y2 + y3 * y3);
        s = waveRed(s); s2 = waveRed(s2);
        if (lane == 0) { redS[wv][co] = s; redS2[wv][co] = s2; }
    }
    __syncthreads();
    if (tid < 32) {
        atomicAdd(&sum[co0 + tid], (redS[0][tid] + redS[1][tid]) + (redS[2][tid] + redS[3][tid]));
    } else if (tid < 64) {
        int c = tid - 32;
        atomicAdd(&sumsq[co0 + c], (redS2[0][c] + redS2[1][c]) + (redS2[2][c] + redS2[3][c]));
    }
}

__global__ void finalize_c0(const double* __restrict__ sum, const double* __restrict__ sumsq,
                            const float* __restrict__ g, const float* __restrict__ b,
                            double* __restrict__ M, double* __restrict__ A,
                            double* __restrict__ BB) {
    int c = threadIdx.x;    // 128
    double m = sum[c] / 262144.0;
    double var = sumsq[c] / 262144.0 - m * m;
    M[c]  = m;
    A[c]  = (double)g[c] / sqrt(var + 1e-5);
    BB[c] = (double)b[c];
}

// ---------------------------------------------------------------- conv0 pack
__global__ __launch_bounds__(256, 1) void conv0_pack3(const float* __restrict__ x,
                                                      const float* __restrict__ w0,
                                                      const double* __restrict__ M,
                                                      const double* __restrict__ A,
                                                      const double* __restrict__ BB,
                                                      u64* __restrict__ A0) {
    __shared__ float xs[3072];
    __shared__ float wsh[3456];
    __shared__ double msh[128], ash[128], bsh[128];
    int tid = threadIdx.x, n = blockIdx.x >> 2;
    int pos = ((blockIdx.x & 3) << 8) + tid;
    for (int i = tid; i < 3072; i += 256) xs[i] = x[n * 3072 + i];
    for (int i = tid; i < 3456; i += 256) {
        int co = i / 27, j = i % 27;    // tap-major
        int ci = j % 3, k = j / 3;
        wsh[i] = w0[co * 27 + ci * 9 + k];
    }
    if (tid < 128) { msh[tid] = M[tid]; ash[tid] = A[tid]; bsh[tid] = BB[tid]; }
    __syncthreads();

    int h = pos >> 5, w = pos & 31;
    float xv[27];
    #pragma unroll
    for (int kh = 0; kh < 3; ++kh) {
        #pragma unroll
        for (int kw = 0; kw < 3; ++kw) {
            #pragma unroll
            for (int ci = 0; ci < 3; ++ci) {
                int ih = h + kh - 1, iw = w + kw - 1;
                bool ok = (unsigned)ih < 32u && (unsigned)iw < 32u;
                xv[(kh * 3 + kw) * 3 + ci] = ok ? xs[ci * 1024 + ih * 32 + iw] : 0.0f;
            }
        }
    }
    u64 b0 = 0, b1 = 0;
    #pragma unroll 4
    for (int co = 0; co < 128; ++co) {
        #pragma clang fp contract(off)
        float acc = 0.f;
        const float* wp = &wsh[co * 27];
        #pragma unroll
        for (int j = 0; j < 27; ++j) acc = __builtin_fmaf(xv[j], wp[j], acc);
        double t = ash[co] * ((double)acc - msh[co]) + bsh[co];
        u64 bit = t > 0.0 ? 1ull : 0ull;
        if (co < 64) b0 |= bit << co; else b1 |= bit << (co - 64);
    }
    size_t p = (size_t)n * 1024 + pos;
    A0[p * 2] = b0; A0[p * 2 + 1] = b1;
}

// ---------------------------------------------------------------- weight bit-pack
__global__ __launch_bounds__(256) void pack_w(const float* __restrict__ w,
                                              u64* __restrict__ Wb, int Ci, int Co) {
    int widx = blockIdx.x * 4 + (threadIdx.x >> 6);
    int lane = threadIdx.x & 63;
    int CW = Ci >> 6;
    int co = widx % Co;
    int rest = widx / Co;
    int cw = rest % CW;
    int k = rest / CW;
    int kh = k / 3, kw = k % 3;
    int ci = (cw << 6) | lane;
    float v = w[((size_t)(co * Ci + ci) * 3 + kh) * 3 + kw];
    u64 m = __ballot(v > 0.0f);
    if (lane == 0) Wb[widx] = m;
}

// ---------------------------------------------------------------- LDS-staged binary conv (R1 proven kernel)
// ONLY change vs R1: the final per-channel reduction goes to a 256-slot
// spread partial array (slot = bid&255) instead of 2 contended cache lines.
// Theory: contended end-of-block atomics hold wave slots (retire waits on
// RMW completion at a few L2 lines) -> low occupancy + low VALUBusy across
// all bconv variants. Spreading drops per-address contention ~256x.
template <int CW, int CO, int HI, bool POOL>
__global__ __launch_bounds__(256, 2) void bconv_lds(const u64* __restrict__ A,
                                                    const u64* __restrict__ Wb,
                                                    short* __restrict__ dots,
                                                    i64* __restrict__ psum) {
    constexpr int WI = HI;
    constexpr int HO = POOL ? HI / 2 : HI;
    constexpr int WO = POOL ? WI / 2 : WI;
    constexpr int NR = POOL ? 4 : 3;
    constexpr int NCOL = POOL ? 4 : 3;
    constexpr int CPB = (CO < 256) ? CO : 256;
    constexpr int BPR = CO / CPB;
    constexpr int WSPLIT = 256 / CPB;
    constexpr int WOT = WO / WSPLIT;
    constexpr int CH = CW / 2;
    constexpr int LROW = (WI + 2) * CW;
    constexpr int NWORD = NR * LROW;
    constexpr int NC = POOL ? 4 : 1;

    __shared__ alignas(16) u64 xs[NWORD];

    const int tid = threadIdx.x;
    const int bid = blockIdx.x;
    const int coh = bid % BPR;
    const int rest = bid / BPR;
    const int ho = rest % HO;
    const int n = rest / HO;
    const int co = coh * CPB + (tid % CPB);
    const int wo0 = (tid / CPB) * WOT;
    const int hbase = POOL ? 2 * ho - 1 : ho - 1;

    const u64* An = A + (size_t)n * HI * WI * CW;
    for (int i = tid; i < NWORD; i += 256) {
        int r = i / LROW;
        int rem = i - r * LROW;
        int c = rem / CW;
        int ch = rem - c * CW;
        int ih = hbase + r, iw = c - 1;
        u64 v = 0;
        if ((unsigned)ih < (unsigned)HI && (unsigned)iw < (unsigned)WI)
            v = An[(size_t)(ih * WI + iw) * CW + ch];
        xs[i] = v;
    }
    __syncthreads();

    int q[WOT * NC];
    #pragma unroll
    for (int i = 0; i < WOT * NC; ++i) q[i] = 0;
    int P[9];
    #pragma unroll
    for (int k = 0; k < 9; ++k) P[k] = 0;

    const int c0 = POOL ? 2 * wo0 : wo0;

    #pragma unroll 1
    for (int ch2 = 0; ch2 < CH; ++ch2) {
        u64 wa[9], wb[9];
        #pragma unroll
        for (int k = 0; k < 9; ++k) {
            wa[k] = Wb[(size_t)(k * CW + 2 * ch2) * CO + co];
            wb[k] = Wb[(size_t)(k * CW + 2 * ch2 + 1) * CO + co];
        }
        #pragma unroll
        for (int k = 0; k < 9; ++k) P[k] += __popcll(wa[k]) + __popcll(wb[k]);

        u64 wx[NR][NCOL], wy[NR][NCOL];
        #pragma unroll
        for (int s = 0; s < 2; ++s) {
            #pragma unroll
            for (int r = 0; r < NR; ++r) {
                const ulonglong2 v = *(const ulonglong2*)&xs[r * LROW + (c0 + s) * CW + 2 * ch2];
                wx[r][s] = v.x; wy[r][s] = v.y;
            }
        }
        #pragma unroll
        for (int j = 0; j < WOT; ++j) {
            if constexpr (!POOL) {
                #pragma unroll
                for (int r = 0; r < NR; ++r) {
                    const ulonglong2 v = *(const ulonglong2*)&xs[r * LROW + (c0 + j + 2) * CW + 2 * ch2];
                    wx[r][(j + 2) % 3] = v.x; wy[r][(j + 2) % 3] = v.y;
                }
                int qq = 0;
                #pragma unroll
                for (int kh = 0; kh < 3; ++kh) {
                    #pragma unroll
                    for (int kw = 0; kw < 3; ++kw) {
                        const int sl = (j + kw) % 3;
                        qq += __popcll(wx[kh][sl] ^ wa[kh * 3 + kw])
                            + __popcll(wy[kh][sl] ^ wb[kh * 3 + kw]);
                    }
                }
                q[j] += qq;
            } else {
                #pragma unroll
                for (int s = 2; s < 4; ++s) {
                    const int sl = (2 * j + s) & 3;
                    #pragma unroll
                    for (int r = 0; r < NR; ++r) {
                        const ulonglong2 v = *(const ulonglong2*)&xs[r * LROW + (c0 + 2 * j + s) * CW + 2 * ch2];
                        wx[r][sl] = v.x; wy[r][sl] = v.y;
                    }
                }
                #pragma unroll
                for (int py = 0; py < 2; ++py) {
                    #pragma unroll
                    for (int px = 0; px < 2; ++px) {
                        int qq = 0;
                        #pragma unroll
                        for (int kh = 0; kh < 3; ++kh) {
                            #pragma unroll
                            for (int kw = 0; kw < 3; ++kw) {
                                const int sl = (2 * j + px + kw) & 3;
                                qq += __popcll(wx[py + kh][sl] ^ wa[kh * 3 + kw])
                                    + __popcll(wy[py + kh][sl] ^ wb[kh * 3 + kw]);
                            }
                        }
                        q[j * 4 + py * 2 + px] += qq;
                    }
                }
            }
        }
    }

    const int prT = P[0] + P[1] + P[2];
    const int prB = P[6] + P[7] + P[8];
    const int pcL = P[0] + P[3] + P[6];
    const int pcR = P[2] + P[5] + P[8];
    const int k00 = P[0], k02 = P[2], k20 = P[6], k22 = P[8];

    int accS = 0, accS2 = 0;
    #pragma unroll
    for (int j = 0; j < WOT; ++j) {
        const int wo = wo0 + j;
        int best;
        if constexpr (!POOL) {
            const int rT = (ho == 0), rB = (ho == HI - 1);
            const int cL = (wo == 0), cR = (wo == WI - 1);
            const int nv = (3 - rT - rB) * (3 - cL - cR);
            const int pad = (rT ? prT : 0) + (rB ? prB : 0) + (cL ? pcL : 0) + (cR ? pcR : 0)
                          - ((rT & cL) ? k00 : 0) - ((rT & cR) ? k02 : 0)
                          - ((rB & cL) ? k20 : 0) - ((rB & cR) ? k22 : 0);
            best = 64 * CW * nv + 2 * pad - 2 * q[j];
        } else {
            best = -(1 << 30);
            #pragma unroll
            for (int py = 0; py < 2; ++py) {
                #pragma unroll
                for (int px = 0; px < 2; ++px) {
                    const int hc = 2 * ho + py, wc = 2 * wo + px;
                    const int rT = (hc == 0), rB = (hc == HI - 1);
                    const int cL = (wc == 0), cR = (wc == WI - 1);
                    const int nv = (3 - rT - rB) * (3 - cL - cR);
                    const int pad = (rT ? prT : 0) + (rB ? prB : 0) + (cL ? pcL : 0) + (cR ? pcR : 0)
                                  - ((rT & cL) ? k00 : 0) - ((rT & cR) ? k02 : 0)
                                  - ((rB & cL) ? k20 : 0) - ((rB & cR) ? k22 : 0);
                    const int d = 64 * CW * nv + 2 * pad - 2 * q[j * 4 + py * 2 + px];
                    best = d > best ? d : best;
                }
            }
        }
        dots[(size_t)((n * HO + ho) * WO + wo) * CO + co] = (short)best;
        accS += best;
        accS2 += best * best;
    }
    // spread-slot partial reduction (slot stride 1024 i64 = 2*512 max-CO)
    const int slot = bid & 255;
    atomicAdd((u64*)&psum[(size_t)slot * 1024 + co], (u64)(i64)accS);
    atomicAdd((u64*)&psum[(size_t)slot * 1024 + 512 + co], (u64)(i64)accS2);
}

// fold the 256 slots into sums[c], self-zeroing the slots for the next layer
__global__ __launch_bounds__(256) void reduce_part(i64* __restrict__ psum,
                                                   i64* __restrict__ sums, int CO) {
    int c = blockIdx.x;
    int t = threadIdx.x;
    i64 a = psum[(size_t)t * 1024 + c];
    i64 b = psum[(size_t)t * 1024 + 512 + c];
    psum[(size_t)t * 1024 + c] = 0;
    psum[(size_t)t * 1024 + 512 + c] = 0;
    #pragma unroll
    for (int o = 32; o > 0; o >>= 1) { a += __shfl_down(a, o, 64); b += __shfl_down(b, o, 64); }
    __shared__ i64 sa[4], sb[4];
    if ((t & 63) == 0) { sa[t >> 6] = a; sb[t >> 6] = b; }
    __syncthreads();
    if (t == 0) {
        sums[c]      = sa[0] + sa[1] + sa[2] + sa[3];
        sums[CO + c] = sb[0] + sb[1] + sb[2] + sb[3];
    }
}

__global__ void finalize_bn(const i64* __restrict__ sums,
                            const float* __restrict__ g, const float* __restrict__ b,
                            int CO, double cnt, double* __restrict__ M,
                            double* __restrict__ A, double* __restrict__ BB) {
    int c = blockIdx.x * blockDim.x + threadIdx.x;
    if (c >= CO) return;
    double m = (double)sums[c] / cnt;
    double var = (double)sums[CO + c] / cnt - m * m;
    M[c]  = m;
    A[c]  = (double)g[c] / sqrt(var + 1e-5);
    BB[c] = (double)b[c];
}

// ---------------------------------------------------------------- binarize + bit-pack
template <int CO>
__global__ __launch_bounds__(256) void binpack_k(const short* __restrict__ xin,
                                                 const double* __restrict__ M,
                                                 const double* __restrict__ A,
                                                 const double* __restrict__ BB,
                                                 u64* __restrict__ Ab) {
    constexpr int CWo = CO / 64;
    int widx = blockIdx.x * 4 + (threadIdx.x >> 6);
    int lane = threadIdx.x & 63;
    int w = widx & (CWo - 1);
    int p = widx / CWo;
    int c = (w << 6) | lane;
    double t = A[c] * ((double)xin[(size_t)p * CO + c] - M[c]) + BB[c];
    u64 m = __ballot(t > 0.0);
    if (lane == 0) Ab[widx] = m;
}

// ---------------------------------------------------------------- FC head
__global__ __launch_bounds__(256) void fc_k(const short* __restrict__ x5,
                                            const double* __restrict__ M,
                                            const double* __restrict__ A,
                                            const double* __restrict__ BB,
                                            const float* __restrict__ wfc,
                                            const float* __restrict__ bfc,
                                            float* __restrict__ out) {
    int n = blockIdx.x / 10, k = blockIdx.x % 10;
    double acc = 0.0;
    for (int i = threadIdx.x; i < 8192; i += 256) {
        int c = i >> 4, hw = i & 15, h = hw >> 2, ww = hw & 3;
        double t = A[c] * ((double)x5[(size_t)((n * 4 + h) * 4 + ww) * 512 + c] - M[c]) + BB[c];
        t = t < -1.0 ? -1.0 : (t > 1.0 ? 1.0 : t);
        acc += t * (double)wfc[(size_t)k * 8192 + i];
    }
    acc = waveRed(acc);
    __shared__ double sd[4];
    if ((threadIdx.x & 63) == 0) sd[threadIdx.x >> 6] = acc;
    __syncthreads();
    if (threadIdx.x == 0)
        out[n * 10 + k] = (float)(sd[0] + sd[1] + sd[2] + sd[3] + (double)bfc[k]);
}

// ---------------------------------------------------------------- launch
extern "C" void kernel_launch(void* const* d_in, const int* in_sizes, int n_in,
                              void* d_out, int out_size, void* d_ws, size_t ws_size,
                              hipStream_t stream) {
    (void)in_sizes; (void)n_in; (void)out_size; (void)ws_size;

    const float* x   = (const float*)d_in[0];
    const float* w0  = (const float*)d_in[1];
    const float* g0  = (const float*)d_in[2];
    const float* b0  = (const float*)d_in[3];
    const float* w1  = (const float*)d_in[4];
    const float* g1  = (const float*)d_in[5];
    const float* b1  = (const float*)d_in[6];
    const float* w2  = (const float*)d_in[7];
    const float* g2  = (const float*)d_in[8];
    const float* b2  = (const float*)d_in[9];
    const float* w3  = (const float*)d_in[10];
    const float* g3  = (const float*)d_in[11];
    const float* b3  = (const float*)d_in[12];
    const float* w4  = (const float*)d_in[13];
    const float* g4  = (const float*)d_in[14];
    const float* b4  = (const float*)d_in[15];
    const float* w5  = (const float*)d_in[16];
    const float* g5  = (const float*)d_in[17];
    const float* b5  = (const float*)d_in[18];
    const float* wfc = (const float*)d_in[19];
    const float* bfc = (const float*)d_in[20];
    float* out = (float*)d_out;

    // ---- workspace layout (~45.2 MB) ----
    char* ws = (char*)d_ws;
    double* sum0   = (double*)ws;                  // 128
    double* sumsq0 = sum0 + 128;                   // 128
    i64* isums = (i64*)(sumsq0 + 128);             // 5 layers * 1024
    // zero span: 2048 + 40960 = 43008 bytes
    double* M  = (double*)(ws + 65536);            // 6*512
    double* A  = M + 3072;
    double* BB = A + 3072;
    char* p = ws + 65536 + 73728;
    u64* A0 = (u64*)p;  p += (size_t)262144 * 2 * 8;   // 4 MiB
    u64* A1 = (u64*)p;  p += (size_t)65536 * 2 * 8;    // 1 MiB
    u64* A2 = (u64*)p;  p += (size_t)65536 * 4 * 8;    // 2 MiB
    u64* A3 = (u64*)p;  p += (size_t)16384 * 4 * 8;    // 0.5 MiB
    u64* A4 = (u64*)p;  p += (size_t)16384 * 8 * 8;    // 1 MiB
    u64* Wb1 = (u64*)p; p += 2304 * 8;
    u64* Wb2 = (u64*)p; p += 4608 * 8;
    u64* Wb3 = (u64*)p; p += 9216 * 8;
    u64* Wb4 = (u64*)p; p += 18432 * 8;
    u64* Wb5 = (u64*)p; p += 36864 * 8;
    p = (char*)(((uintptr_t)p + 255) & ~(uintptr_t)255);
    i64* psum = (i64*)p; p += (size_t)256 * 1024 * 8;  // 2 MiB spread partials
    p = (char*)(((uintptr_t)p + 255) & ~(uintptr_t)255);
    short* dots = (short*)p;                       // max 65536*256*2 = 33.5 MB

    hipMemsetAsync(d_ws, 0, 43008, stream);
    hipMemsetAsync(psum, 0, (size_t)256 * 1024 * 8, stream);

    // weight bit-packs
    pack_w<<<576,  256, 0, stream>>>(w1, Wb1, 128, 128);
    pack_w<<<1152, 256, 0, stream>>>(w2, Wb2, 128, 256);
    pack_w<<<2304, 256, 0, stream>>>(w3, Wb3, 256, 256);
    pack_w<<<4608, 256, 0, stream>>>(w4, Wb4, 256, 512);
    pack_w<<<9216, 256, 0, stream>>>(w5, Wb5, 512, 512);

    // conv0 (np-f32 FMA (kh,kw,ci)) + BN0 + pack
    conv0_sums3<<<dim3(4, 256), 256, 0, stream>>>(x, w0, sum0, sumsq0);
    finalize_c0<<<1, 128, 0, stream>>>(sum0, sumsq0, g0, b0, M, A, BB);
    conv0_pack3<<<1024, 256, 0, stream>>>(x, w0, M, A, BB, A0);

    // L1: 128->128 @32x32, pool -> 16x16
    bconv_lds<2, 128, 32, true><<<4096, 256, 0, stream>>>(A0, Wb1, dots, psum);
    reduce_part<<<128, 256, 0, stream>>>(psum, isums, 128);
    finalize_bn<<<1, 128, 0, stream>>>(isums, g1, b1, 128, 65536.0, M + 512, A + 512, BB + 512);
    binpack_k<128><<<32768, 256, 0, stream>>>(dots, M + 512, A + 512, BB + 512, A1);

    // L2: 128->256 @16x16
    bconv_lds<2, 256, 16, false><<<4096, 256, 0, stream>>>(A1, Wb2, dots, psum);
    reduce_part<<<256, 256, 0, stream>>>(psum, isums + 1024, 256);
    finalize_bn<<<1, 256, 0, stream>>>(isums + 1024, g2, b2, 256, 65536.0, M + 1024, A + 1024, BB + 1024);
    binpack_k<256><<<65536, 256, 0, stream>>>(dots, M + 1024, A + 1024, BB + 1024, A2);

    // L3: 256->256 @16x16, pool -> 8x8
    bconv_lds<4, 256, 16, true><<<2048, 256, 0, stream>>>(A2, Wb3, dots, psum);
    reduce_part<<<256, 256, 0, stream>>>(psum, isums + 2048, 256);
    finalize_bn<<<1, 256, 0, stream>>>(isums + 2048, g3, b3, 256, 16384.0, M + 1536, A + 1536, BB + 1536);
    binpack_k<256><<<16384, 256, 0, stream>>>(dots, M + 1536, A + 1536, BB + 1536, A3);

    // L4: 256->512 @8x8
    bconv_lds<4, 512, 8, false><<<4096, 256, 0, stream>>>(A3, Wb4, dots, psum);
    reduce_part<<<512, 256, 0, stream>>>(psum, isums + 3072, 512);
    finalize_bn<<<1, 512, 0, stream>>>(isums + 3072, g4, b4, 512, 16384.0, M + 2048, A + 2048, BB + 2048);
    binpack_k<512><<<32768, 256, 0, stream>>>(dots, M + 2048, A + 2048, BB + 2048, A4);

    // L5: 512->512 @8x8, pool -> 4x4
    bconv_lds<8, 512, 8, true><<<2048, 256, 0, stream>>>(A4, Wb5, dots, psum);
    reduce_part<<<512, 256, 0, stream>>>(psum, isums + 4096, 512);
    finalize_bn<<<1, 512, 0, stream>>>(isums + 4096, g5, b5, 512, 4096.0, M + 2560, A + 2560, BB + 2560);

    // FC head
    fc_k<<<2560, 256, 0, stream>>>(dots, M + 2560, A + 2560, BB + 2560, wfc, bfc, out);
}

// Round 8
// 748.385 us; speedup vs baseline: 1.4705x; 1.0294x over previous
//
#include <hip/hip_runtime.h>
#include <cstdint>
#include <cstddef>

using u64 = unsigned long long;
using i64 = long long;

#define DEVI __device__ __forceinline__

// ---------------------------------------------------------------- reductions
DEVI double waveRed(double v) {
    #pragma unroll
    for (int o = 32; o > 0; o >>= 1) v += __shfl_down(v, o, 64);
    return v;
}

// ---------------------------------------------------------------- conv0 stats (np-f32: FMA chain, (kh,kw,ci) order)
__global__ __launch_bounds__(256, 1) void conv0_sums3(const float* __restrict__ x,
                                                      const float* __restrict__ w0,
                                                      double* __restrict__ sum,
                                                      double* __restrict__ sumsq) {
    __shared__ float xs[3072];
    __shared__ float wsh[864];          // 32 co * 27, tap-major
    __shared__ double redS[4][32], redS2[4][32];
    int tid = threadIdx.x, n = blockIdx.y, co0 = blockIdx.x * 32;
    for (int i = tid; i < 3072; i += 256) xs[i] = x[n * 3072 + i];
    for (int i = tid; i < 864; i += 256) {
        int co = i / 27, j = i % 27;    // j = tap-major (kh*3+kw)*3 + ci
        int ci = j % 3, k = j / 3;
        wsh[i] = w0[(co0 + co) * 27 + ci * 9 + k];
    }
    __syncthreads();

    float xv[4][27];
    #pragma unroll
    for (int k = 0; k < 4; ++k) {
        int pos = tid + k * 256, h = pos >> 5, w = pos & 31;
        #pragma unroll
        for (int kh = 0; kh < 3; ++kh) {
            #pragma unroll
            for (int kw = 0; kw < 3; ++kw) {
                #pragma unroll
                for (int ci = 0; ci < 3; ++ci) {
                    int ih = h + kh - 1, iw = w + kw - 1;
                    bool ok = (unsigned)ih < 32u && (unsigned)iw < 32u;
                    xv[k][(kh * 3 + kw) * 3 + ci] = ok ? xs[ci * 1024 + ih * 32 + iw] : 0.0f;
                }
            }
        }
    }
    int lane = tid & 63, wv = tid >> 6;
    for (int co = 0; co < 32; ++co) {
        #pragma clang fp contract(off)
        const float* wp = &wsh[co * 27];
        float a0 = 0.f, a1 = 0.f, a2 = 0.f, a3 = 0.f;
        #pragma unroll
        for (int j = 0; j < 27; ++j) {
            float wj = wp[j];
            a0 = __builtin_fmaf(xv[0][j], wj, a0);
            a1 = __builtin_fmaf(xv[1][j], wj, a1);
            a2 = __builtin_fmaf(xv[2][j], wj, a2);
            a3 = __builtin_fmaf(xv[3][j], wj, a3);
        }
        double y0 = a0, y1 = a1, y2 = a2, y3 = a3;
        double s  = (y0 + y1) + (y2 + y3);
        double s2 = (y0 * y0 + y1 * y1) + (y2 * y2 + y3 * y3);
        s = waveRed(s); s2 = waveRed(s2);
        if (lane == 0) { redS[wv][co] = s; redS2[wv][co] = s2; }
    }
    __syncthreads();
    if (tid < 32) {
        atomicAdd(&sum[co0 + tid], (redS[0][tid] + redS[1][tid]) + (redS[2][tid] + redS[3][tid]));
    } else if (tid < 64) {
        int c = tid - 32;
        atomicAdd(&sumsq[co0 + c], (redS2[0][c] + redS2[1][c]) + (redS2[2][c] + redS2[3][c]));
    }
}

__global__ void finalize_c0(const double* __restrict__ sum, const double* __restrict__ sumsq,
                            const float* __restrict__ g, const float* __restrict__ b,
                            double* __restrict__ M, double* __restrict__ A,
                            double* __restrict__ BB) {
    int c = threadIdx.x;    // 128
    double m = sum[c] / 262144.0;
    double var = sumsq[c] / 262144.0 - m * m;
    M[c]  = m;
    A[c]  = (double)g[c] / sqrt(var + 1e-5);
    BB[c] = (double)b[c];
}

// ---------------------------------------------------------------- conv0 pack
__global__ __launch_bounds__(256, 1) void conv0_pack3(const float* __restrict__ x,
                                                      const float* __restrict__ w0,
                                                      const double* __restrict__ M,
                                                      const double* __restrict__ A,
                                                      const double* __restrict__ BB,
                                                      u64* __restrict__ A0) {
    __shared__ float xs[3072];
    __shared__ float wsh[3456];
    __shared__ double msh[128], ash[128], bsh[128];
    int tid = threadIdx.x, n = blockIdx.x >> 2;
    int pos = ((blockIdx.x & 3) << 8) + tid;
    for (int i = tid; i < 3072; i += 256) xs[i] = x[n * 3072 + i];
    for (int i = tid; i < 3456; i += 256) {
        int co = i / 27, j = i % 27;    // tap-major
        int ci = j % 3, k = j / 3;
        wsh[i] = w0[co * 27 + ci * 9 + k];
    }
    if (tid < 128) { msh[tid] = M[tid]; ash[tid] = A[tid]; bsh[tid] = BB[tid]; }
    __syncthreads();

    int h = pos >> 5, w = pos & 31;
    float xv[27];
    #pragma unroll
    for (int kh = 0; kh < 3; ++kh) {
        #pragma unroll
        for (int kw = 0; kw < 3; ++kw) {
            #pragma unroll
            for (int ci = 0; ci < 3; ++ci) {
                int ih = h + kh - 1, iw = w + kw - 1;
                bool ok = (unsigned)ih < 32u && (unsigned)iw < 32u;
                xv[(kh * 3 + kw) * 3 + ci] = ok ? xs[ci * 1024 + ih * 32 + iw] : 0.0f;
            }
        }
    }
    u64 b0 = 0, b1 = 0;
    #pragma unroll 4
    for (int co = 0; co < 128; ++co) {
        #pragma clang fp contract(off)
        float acc = 0.f;
        const float* wp = &wsh[co * 27];
        #pragma unroll
        for (int j = 0; j < 27; ++j) acc = __builtin_fmaf(xv[j], wp[j], acc);
        double t = ash[co] * ((double)acc - msh[co]) + bsh[co];
        u64 bit = t > 0.0 ? 1ull : 0ull;
        if (co < 64) b0 |= bit << co; else b1 |= bit << (co - 64);
    }
    size_t p = (size_t)n * 1024 + pos;
    A0[p * 2] = b0; A0[p * 2 + 1] = b1;
}

// ---------------------------------------------------------------- weight bit-pack (all 5 layers, one dispatch)
__global__ __launch_bounds__(256) void pack_w_all(const float* __restrict__ w1, u64* __restrict__ Wb1,
                                                  const float* __restrict__ w2, u64* __restrict__ Wb2,
                                                  const float* __restrict__ w3, u64* __restrict__ Wb3,
                                                  const float* __restrict__ w4, u64* __restrict__ Wb4,
                                                  const float* __restrict__ w5, u64* __restrict__ Wb5) {
    int blk = blockIdx.x;
    const float* w; u64* Wb; int Ci, Co, base;
    if (blk < 576)       { w = w1; Wb = Wb1; Ci = 128; Co = 128; base = 0; }
    else if (blk < 1728) { w = w2; Wb = Wb2; Ci = 128; Co = 256; base = 576; }
    else if (blk < 4032) { w = w3; Wb = Wb3; Ci = 256; Co = 256; base = 1728; }
    else if (blk < 8640) { w = w4; Wb = Wb4; Ci = 256; Co = 512; base = 4032; }
    else                 { w = w5; Wb = Wb5; Ci = 512; Co = 512; base = 8640; }
    int widx = (blk - base) * 4 + (threadIdx.x >> 6);
    int lane = threadIdx.x & 63;
    int CW = Ci >> 6;
    int co = widx % Co;
    int rest = widx / Co;
    int cw = rest % CW;
    int k = rest / CW;
    int kh = k / 3, kw = k % 3;
    int ci = (cw << 6) | lane;
    float v = w[((size_t)(co * Ci + ci) * 3 + kh) * 3 + kw];
    u64 m = __ballot(v > 0.0f);
    if (lane == 0) Wb[widx] = m;
}

// ---------------------------------------------------------------- LDS-staged binary conv (R7 proven kernel, EXACT)
// Spread-slot partial reduction (R7): atomics target 256 slots x 2 KB instead
// of 2 cache lines -> contention drop was the 197->90 us win.
template <int CW, int CO, int HI, bool POOL>
__global__ __launch_bounds__(256, 2) void bconv_lds(const u64* __restrict__ A,
                                                    const u64* __restrict__ Wb,
                                                    short* __restrict__ dots,
                                                    i64* __restrict__ psum) {
    constexpr int WI = HI;
    constexpr int HO = POOL ? HI / 2 : HI;
    constexpr int WO = POOL ? WI / 2 : WI;
    constexpr int NR = POOL ? 4 : 3;
    constexpr int NCOL = POOL ? 4 : 3;
    constexpr int CPB = (CO < 256) ? CO : 256;
    constexpr int BPR = CO / CPB;
    constexpr int WSPLIT = 256 / CPB;
    constexpr int WOT = WO / WSPLIT;
    constexpr int CH = CW / 2;
    constexpr int LROW = (WI + 2) * CW;
    constexpr int NWORD = NR * LROW;
    constexpr int NC = POOL ? 4 : 1;

    __shared__ alignas(16) u64 xs[NWORD];

    const int tid = threadIdx.x;
    const int bid = blockIdx.x;
    const int coh = bid % BPR;
    const int rest = bid / BPR;
    const int ho = rest % HO;
    const int n = rest / HO;
    const int co = coh * CPB + (tid % CPB);
    const int wo0 = (tid / CPB) * WOT;
    const int hbase = POOL ? 2 * ho - 1 : ho - 1;

    const u64* An = A + (size_t)n * HI * WI * CW;
    for (int i = tid; i < NWORD; i += 256) {
        int r = i / LROW;
        int rem = i - r * LROW;
        int c = rem / CW;
        int ch = rem - c * CW;
        int ih = hbase + r, iw = c - 1;
        u64 v = 0;
        if ((unsigned)ih < (unsigned)HI && (unsigned)iw < (unsigned)WI)
            v = An[(size_t)(ih * WI + iw) * CW + ch];
        xs[i] = v;
    }
    __syncthreads();

    int q[WOT * NC];
    #pragma unroll
    for (int i = 0; i < WOT * NC; ++i) q[i] = 0;
    int P[9];
    #pragma unroll
    for (int k = 0; k < 9; ++k) P[k] = 0;

    const int c0 = POOL ? 2 * wo0 : wo0;

    #pragma unroll 1
    for (int ch2 = 0; ch2 < CH; ++ch2) {
        u64 wa[9], wb[9];
        #pragma unroll
        for (int k = 0; k < 9; ++k) {
            wa[k] = Wb[(size_t)(k * CW + 2 * ch2) * CO + co];
            wb[k] = Wb[(size_t)(k * CW + 2 * ch2 + 1) * CO + co];
        }
        #pragma unroll
        for (int k = 0; k < 9; ++k) P[k] += __popcll(wa[k]) + __popcll(wb[k]);

        u64 wx[NR][NCOL], wy[NR][NCOL];
        #pragma unroll
        for (int s = 0; s < 2; ++s) {
            #pragma unroll
            for (int r = 0; r < NR; ++r) {
                const ulonglong2 v = *(const ulonglong2*)&xs[r * LROW + (c0 + s) * CW + 2 * ch2];
                wx[r][s] = v.x; wy[r][s] = v.y;
            }
        }
        #pragma unroll
        for (int j = 0; j < WOT; ++j) {
            if constexpr (!POOL) {
                #pragma unroll
                for (int r = 0; r < NR; ++r) {
                    const ulonglong2 v = *(const ulonglong2*)&xs[r * LROW + (c0 + j + 2) * CW + 2 * ch2];
                    wx[r][(j + 2) % 3] = v.x; wy[r][(j + 2) % 3] = v.y;
                }
                int qq = 0;
                #pragma unroll
                for (int kh = 0; kh < 3; ++kh) {
                    #pragma unroll
                    for (int kw = 0; kw < 3; ++kw) {
                        const int sl = (j + kw) % 3;
                        qq += __popcll(wx[kh][sl] ^ wa[kh * 3 + kw])
                            + __popcll(wy[kh][sl] ^ wb[kh * 3 + kw]);
                    }
                }
                q[j] += qq;
            } else {
                #pragma unroll
                for (int s = 2; s < 4; ++s) {
                    const int sl = (2 * j + s) & 3;
                    #pragma unroll
                    for (int r = 0; r < NR; ++r) {
                        const ulonglong2 v = *(const ulonglong2*)&xs[r * LROW + (c0 + 2 * j + s) * CW + 2 * ch2];
                        wx[r][sl] = v.x; wy[r][sl] = v.y;
                    }
                }
                #pragma unroll
                for (int py = 0; py < 2; ++py) {
                    #pragma unroll
                    for (int px = 0; px < 2; ++px) {
                        int qq = 0;
                        #pragma unroll
                        for (int kh = 0; kh < 3; ++kh) {
                            #pragma unroll
                            for (int kw = 0; kw < 3; ++kw) {
                                const int sl = (2 * j + px + kw) & 3;
                                qq += __popcll(wx[py + kh][sl] ^ wa[kh * 3 + kw])
                                    + __popcll(wy[py + kh][sl] ^ wb[kh * 3 + kw]);
                            }
                        }
                        q[j * 4 + py * 2 + px] += qq;
                    }
                }
            }
        }
    }

    const int prT = P[0] + P[1] + P[2];
    const int prB = P[6] + P[7] + P[8];
    const int pcL = P[0] + P[3] + P[6];
    const int pcR = P[2] + P[5] + P[8];
    const int k00 = P[0], k02 = P[2], k20 = P[6], k22 = P[8];

    int accS = 0, accS2 = 0;
    #pragma unroll
    for (int j = 0; j < WOT; ++j) {
        const int wo = wo0 + j;
        int best;
        if constexpr (!POOL) {
            const int rT = (ho == 0), rB = (ho == HI - 1);
            const int cL = (wo == 0), cR = (wo == WI - 1);
            const int nv = (3 - rT - rB) * (3 - cL - cR);
            const int pad = (rT ? prT : 0) + (rB ? prB : 0) + (cL ? pcL : 0) + (cR ? pcR : 0)
                          - ((rT & cL) ? k00 : 0) - ((rT & cR) ? k02 : 0)
                          - ((rB & cL) ? k20 : 0) - ((rB & cR) ? k22 : 0);
            best = 64 * CW * nv + 2 * pad - 2 * q[j];
        } else {
            best = -(1 << 30);
            #pragma unroll
            for (int py = 0; py < 2; ++py) {
                #pragma unroll
                for (int px = 0; px < 2; ++px) {
                    const int hc = 2 * ho + py, wc = 2 * wo + px;
                    const int rT = (hc == 0), rB = (hc == HI - 1);
                    const int cL = (wc == 0), cR = (wc == WI - 1);
                    const int nv = (3 - rT - rB) * (3 - cL - cR);
                    const int pad = (rT ? prT : 0) + (rB ? prB : 0) + (cL ? pcL : 0) + (cR ? pcR : 0)
                                  - ((rT & cL) ? k00 : 0) - ((rT & cR) ? k02 : 0)
                                  - ((rB & cL) ? k20 : 0) - ((rB & cR) ? k22 : 0);
                    const int d = 64 * CW * nv + 2 * pad - 2 * q[j * 4 + py * 2 + px];
                    best = d > best ? d : best;
                }
            }
        }
        dots[(size_t)((n * HO + ho) * WO + wo) * CO + co] = (short)best;
        accS += best;
        accS2 += best * best;
    }
    // spread-slot partial reduction (slot stride 1024 i64 = 2*512 max-CO)
    const int slot = bid & 255;
    atomicAdd((u64*)&psum[(size_t)slot * 1024 + co], (u64)(i64)accS);
    atomicAdd((u64*)&psum[(size_t)slot * 1024 + 512 + co], (u64)(i64)accS2);
}

// fused: fold the 256 spread slots (self-zeroing) + BN finalize in one kernel
__global__ __launch_bounds__(256) void reduce_fin(i64* __restrict__ psum,
                                                  const float* __restrict__ g,
                                                  const float* __restrict__ b,
                                                  int CO, double cnt,
                                                  double* __restrict__ M,
                                                  double* __restrict__ A,
                                                  double* __restrict__ BB) {
    int c = blockIdx.x;
    int t = threadIdx.x;
    i64 a = psum[(size_t)t * 1024 + c];
    i64 d = psum[(size_t)t * 1024 + 512 + c];
    psum[(size_t)t * 1024 + c] = 0;
    psum[(size_t)t * 1024 + 512 + c] = 0;
    #pragma unroll
    for (int o = 32; o > 0; o >>= 1) { a += __shfl_down(a, o, 64); d += __shfl_down(d, o, 64); }
    __shared__ i64 sa[4], sb[4];
    if ((t & 63) == 0) { sa[t >> 6] = a; sb[t >> 6] = d; }
    __syncthreads();
    if (t == 0) {
        i64 S  = sa[0] + sa[1] + sa[2] + sa[3];
        i64 S2 = sb[0] + sb[1] + sb[2] + sb[3];
        double m = (double)S / cnt;
        double var = (double)S2 / cnt - m * m;
        M[c]  = m;
        A[c]  = (double)g[c] / sqrt(var + 1e-5);
        BB[c] = (double)b[c];
    }
}

// ---------------------------------------------------------------- binarize + bit-pack (4 words per wave)
template <int CO>
__global__ __launch_bounds__(256) void binpack_k(const short* __restrict__ xin,
                                                 const double* __restrict__ M,
                                                 const double* __restrict__ A,
                                                 const double* __restrict__ BB,
                                                 u64* __restrict__ Ab) {
    constexpr int CWo = CO / 64;
    int lane = threadIdx.x & 63;
    int wbase = (blockIdx.x * 4 + (threadIdx.x >> 6)) * 4;
    #pragma unroll
    for (int k = 0; k < 4; ++k) {
        int widx = wbase + k;
        int w = widx & (CWo - 1);
        int p = widx / CWo;
        int c = (w << 6) | lane;
        double t = A[c] * ((double)xin[(size_t)p * CO + c] - M[c]) + BB[c];
        u64 m = __ballot(t > 0.0);
        if (lane == 0) Ab[widx] = m;
    }
}

// ---------------------------------------------------------------- FC head
__global__ __launch_bounds__(256) void fc_k(const short* __restrict__ x5,
                                            const double* __restrict__ M,
                                            const double* __restrict__ A,
                                            const double* __restrict__ BB,
                                            const float* __restrict__ wfc,
                                            const float* __restrict__ bfc,
                                            float* __restrict__ out) {
    int n = blockIdx.x / 10, k = blockIdx.x % 10;
    double acc = 0.0;
    for (int i = threadIdx.x; i < 8192; i += 256) {
        int c = i >> 4, hw = i & 15, h = hw >> 2, ww = hw & 3;
        double t = A[c] * ((double)x5[(size_t)((n * 4 + h) * 4 + ww) * 512 + c] - M[c]) + BB[c];
        t = t < -1.0 ? -1.0 : (t > 1.0 ? 1.0 : t);
        acc += t * (double)wfc[(size_t)k * 8192 + i];
    }
    acc = waveRed(acc);
    __shared__ double sd[4];
    if ((threadIdx.x & 63) == 0) sd[threadIdx.x >> 6] = acc;
    __syncthreads();
    if (threadIdx.x == 0)
        out[n * 10 + k] = (float)(sd[0] + sd[1] + sd[2] + sd[3] + (double)bfc[k]);
}

// ---------------------------------------------------------------- launch
extern "C" void kernel_launch(void* const* d_in, const int* in_sizes, int n_in,
                              void* d_out, int out_size, void* d_ws, size_t ws_size,
                              hipStream_t stream) {
    (void)in_sizes; (void)n_in; (void)out_size; (void)ws_size;

    const float* x   = (const float*)d_in[0];
    const float* w0  = (const float*)d_in[1];
    const float* g0  = (const float*)d_in[2];
    const float* b0  = (const float*)d_in[3];
    const float* w1  = (const float*)d_in[4];
    const float* g1  = (const float*)d_in[5];
    const float* b1  = (const float*)d_in[6];
    const float* w2  = (const float*)d_in[7];
    const float* g2  = (const float*)d_in[8];
    const float* b2  = (const float*)d_in[9];
    const float* w3  = (const float*)d_in[10];
    const float* g3  = (const float*)d_in[11];
    const float* b3  = (const float*)d_in[12];
    const float* w4  = (const float*)d_in[13];
    const float* g4  = (const float*)d_in[14];
    const float* b4  = (const float*)d_in[15];
    const float* w5  = (const float*)d_in[16];
    const float* g5  = (const float*)d_in[17];
    const float* b5  = (const float*)d_in[18];
    const float* wfc = (const float*)d_in[19];
    const float* bfc = (const float*)d_in[20];
    float* out = (float*)d_out;

    // ---- workspace layout (~45.2 MB) ----
    char* ws = (char*)d_ws;
    double* sum0   = (double*)ws;                  // 128
    double* sumsq0 = sum0 + 128;                   // 128
    i64* isums = (i64*)(sumsq0 + 128);             // (legacy span, kept zeroed)
    (void)isums;
    // zero span: 2048 + 40960 = 43008 bytes
    double* M  = (double*)(ws + 65536);            // 6*512
    double* A  = M + 3072;
    double* BB = A + 3072;
    char* p = ws + 65536 + 73728;
    u64* A0 = (u64*)p;  p += (size_t)262144 * 2 * 8;   // 4 MiB
    u64* A1 = (u64*)p;  p += (size_t)65536 * 2 * 8;    // 1 MiB
    u64* A2 = (u64*)p;  p += (size_t)65536 * 4 * 8;    // 2 MiB
    u64* A3 = (u64*)p;  p += (size_t)16384 * 4 * 8;    // 0.5 MiB
    u64* A4 = (u64*)p;  p += (size_t)16384 * 8 * 8;    // 1 MiB
    u64* Wb1 = (u64*)p; p += 2304 * 8;
    u64* Wb2 = (u64*)p; p += 4608 * 8;
    u64* Wb3 = (u64*)p; p += 9216 * 8;
    u64* Wb4 = (u64*)p; p += 18432 * 8;
    u64* Wb5 = (u64*)p; p += 36864 * 8;
    p = (char*)(((uintptr_t)p + 255) & ~(uintptr_t)255);
    i64* psum = (i64*)p; p += (size_t)256 * 1024 * 8;  // 2 MiB spread partials
    p = (char*)(((uintptr_t)p + 255) & ~(uintptr_t)255);
    short* dots = (short*)p;                       // max 65536*256*2 = 33.5 MB

    hipMemsetAsync(d_ws, 0, 43008, stream);
    hipMemsetAsync(psum, 0, (size_t)256 * 1024 * 8, stream);

    // weight bit-packs (single dispatch, 5 layers)
    pack_w_all<<<17856, 256, 0, stream>>>(w1, Wb1, w2, Wb2, w3, Wb3, w4, Wb4, w5, Wb5);

    // conv0 (np-f32 FMA (kh,kw,ci)) + BN0 + pack
    conv0_sums3<<<dim3(4, 256), 256, 0, stream>>>(x, w0, sum0, sumsq0);
    finalize_c0<<<1, 128, 0, stream>>>(sum0, sumsq0, g0, b0, M, A, BB);
    conv0_pack3<<<1024, 256, 0, stream>>>(x, w0, M, A, BB, A0);

    // L1: 128->128 @32x32, pool -> 16x16
    bconv_lds<2, 128, 32, true><<<4096, 256, 0, stream>>>(A0, Wb1, dots, psum);
    reduce_fin<<<128, 256, 0, stream>>>(psum, g1, b1, 128, 65536.0, M + 512, A + 512, BB + 512);
    binpack_k<128><<<8192, 256, 0, stream>>>(dots, M + 512, A + 512, BB + 512, A1);

    // L2: 128->256 @16x16
    bconv_lds<2, 256, 16, false><<<4096, 256, 0, stream>>>(A1, Wb2, dots, psum);
    reduce_fin<<<256, 256, 0, stream>>>(psum, g2, b2, 256, 65536.0, M + 1024, A + 1024, BB + 1024);
    binpack_k<256><<<16384, 256, 0, stream>>>(dots, M + 1024, A + 1024, BB + 1024, A2);

    // L3: 256->256 @16x16, pool -> 8x8
    bconv_lds<4, 256, 16, true><<<2048, 256, 0, stream>>>(A2, Wb3, dots, psum);
    reduce_fin<<<256, 256, 0, stream>>>(psum, g3, b3, 256, 16384.0, M + 1536, A + 1536, BB + 1536);
    binpack_k<256><<<4096, 256, 0, stream>>>(dots, M + 1536, A + 1536, BB + 1536, A3);

    // L4: 256->512 @8x8
    bconv_lds<4, 512, 8, false><<<4096, 256, 0, stream>>>(A3, Wb4, dots, psum);
    reduce_fin<<<512, 256, 0, stream>>>(psum, g4, b4, 512, 16384.0, M + 2048, A + 2048, BB + 2048);
    binpack_k<512><<<8192, 256, 0, stream>>>(dots, M + 2048, A + 2048, BB + 2048, A4);

    // L5: 512->512 @8x8, pool -> 4x4
    bconv_lds<8, 512, 8, true><<<2048, 256, 0, stream>>>(A4, Wb5, dots, psum);
    reduce_fin<<<512, 256, 0, stream>>>(psum, g5, b5, 512, 4096.0, M + 2560, A + 2560, BB + 2560);

    // FC head
    fc_k<<<2560, 256, 0, stream>>>(dots, M + 2560, A + 2560, BB + 2560, wfc, bfc, out);
}